// Round 12
// baseline (414.497 us; speedup 1.0000x reference)
//
#include <hip/hip_runtime.h>

static constexpr int BB = 16;
static constexpr int NN = 256;
static constexpr int DD = 128;

__device__ __forceinline__ float sigterm(float kv, float q, float we) {
    // we * sigmoid(k+q) with ek=exp(-k), eq=exp(-q) precomputed: 1/(1+ek*eq)
    return we * __builtin_amdgcn_rcpf(fmaf(kv, q, 1.0f));
}

// Tiled GEMM: out[b,r,e] = sum_d x[b,r,d]*W[e,d] (+bias; exp(-.) for q,k).
// grid = 3m * 16b * 8 row-tiles * 2 e-halves = 768 blocks (3/CU), 512 thr.
__global__ __launch_bounds__(512) void qkv_kernel(
    const float* __restrict__ x,
    const float* __restrict__ Wq, const float* __restrict__ bq,
    const float* __restrict__ Wk, const float* __restrict__ Wv,
    float* __restrict__ eq, float* __restrict__ ek, float* __restrict__ vv)
{
    __shared__ float wlds[64 * DD];     // 64 e-rows x 128 d, swizzled (32KB)
    __shared__ float xlds[32][132];     // 32 rows x 128 d, padded (16.9KB)

    const int bid  = blockIdx.x;
    const int m    = bid % 3;
    const int rest = bid / 3;
    const int eh   = rest & 1;
    const int tile = rest >> 1;
    const int b    = tile >> 3;
    const int r0   = (tile & 7) << 5;
    const int t    = threadIdx.x;

    const float* W = (m == 0) ? Wq : (m == 1) ? Wk : Wv;
    float*      op = (m == 0) ? eq : (m == 1) ? ek : vv;

    char* wb = (char*)wlds;
    {
        const float4* wg = (const float4*)(W + (size_t)(eh * 64) * DD);
        #pragma unroll
        for (int rep = 0; rep < 4; ++rep) {
            const int idx = t + (rep << 9);
            const int e   = idx >> 5;
            const int c   = idx & 31;
            const int byte = e * 512 + c * 16;
            *(float4*)(wb + (byte ^ (((e >> 2) & 7) << 4))) = wg[idx];
        }
        const float4* xg = (const float4*)(x + ((size_t)(b * NN + r0)) * DD);
        #pragma unroll
        for (int rep = 0; rep < 2; ++rep) {
            const int idx = t + (rep << 9);
            *(float4*)&xlds[idx >> 5][(idx & 31) << 2] = xg[idx];
        }
    }
    __syncthreads();

    const int er = t & 15;
    const int rg = t >> 4;
    float4 acc = {0.f, 0.f, 0.f, 0.f};
    #pragma unroll 8
    for (int d4 = 0; d4 < DD / 4; ++d4) {
        const float4 xv = *(const float4*)&xlds[rg][d4 << 2];
        float4 w4[4];
        #pragma unroll
        for (int cc = 0; cc < 4; ++cc) {
            const int e = er * 4 + cc;
            const int byte = e * 512 + d4 * 16;
            w4[cc] = *(const float4*)(wb + (byte ^ (((e >> 2) & 7) << 4)));
        }
        acc.x = fmaf(xv.x, w4[0].x, fmaf(xv.y, w4[0].y, fmaf(xv.z, w4[0].z, fmaf(xv.w, w4[0].w, acc.x))));
        acc.y = fmaf(xv.x, w4[1].x, fmaf(xv.y, w4[1].y, fmaf(xv.z, w4[1].z, fmaf(xv.w, w4[1].w, acc.y))));
        acc.z = fmaf(xv.x, w4[2].x, fmaf(xv.y, w4[2].y, fmaf(xv.z, w4[2].z, fmaf(xv.w, w4[2].w, acc.z))));
        acc.w = fmaf(xv.x, w4[3].x, fmaf(xv.y, w4[3].y, fmaf(xv.z, w4[3].z, fmaf(xv.w, w4[3].w, acc.w))));
    }

    const int eg = eh * 64 + er * 4;
    float4 o = acc;
    if (m == 0) {
        const float4 b4 = *(const float4*)(bq + eg);
        o.x = __expf(-(o.x + b4.x)); o.y = __expf(-(o.y + b4.y));
        o.z = __expf(-(o.z + b4.z)); o.w = __expf(-(o.w + b4.w));
    } else if (m == 1) {
        o.x = __expf(-o.x); o.y = __expf(-o.y);
        o.z = __expf(-o.z); o.w = __expf(-o.w);
    }
    *(float4*)(op + ((size_t)(b * NN + r0 + rg)) * DD + eg) = o;
}

// grid = 16 b * 64 j-tiles = 1024 blocks, 512 threads, 4 j per block.
// LDS 40.6KB -> 3 blocks/CU; __launch_bounds__(512,6) caps VGPR ~85 (no spill,
// Phase-B live state ~35). No Phase-D reduce: thread = (j, d) over all 256 i.
__global__ __launch_bounds__(512, 6) void attn_kernel(
    const int* __restrict__ A, const float* __restrict__ We,
    const float* __restrict__ eq, const float* __restrict__ ek,
    const float* __restrict__ vv, float* __restrict__ out)
{
    __shared__ float vs[64][132];    // v chunk (33792 B)
    __shared__ float eqs[4][132];    // 2112 B
    __shared__ float wes[DD];        // 512 B
    __shared__ float ssm[4][260];    // 4160 B
    __shared__ float smC;

    // bijective XCD swizzle: 1024 wgs / 8 XCDs = 128 contiguous per XCD
    const int bid = (int)((blockIdx.x & 7) * 128 + (blockIdx.x >> 3));
    const int b  = bid >> 6;
    const int j0 = (bid & 63) << 2;
    const int t  = threadIdx.x;

    // ---- Phase A: stage 4 q-rows + We; wave 7 computes C = 0.5*sum(We) ----
    if (t < 128) {
        const int row = t >> 5, col = (t & 31) << 2;
        *(float4*)&eqs[row][col] =
            *(const float4*)(eq + ((size_t)(b * NN + j0 + row)) * DD + col);
    } else if (t < 160) {
        const int l = t - 128;
        *(float4*)&wes[l << 2] = ((const float4*)We)[l];
    } else if (t >= 448) {
        const int lane = t - 448;
        float w = We[lane] + We[lane + 64];
        #pragma unroll
        for (int o = 32; o > 0; o >>= 1) w += __shfl_xor(w, o);
        if (lane == 0) smC = 0.5f * w;
    }
    __syncthreads();

    // ---- Phase B: thread = (i, 2 j's). 8 sigterms/iter; trans-pipe bound. ----
    {
        const float C = smC;
        const int i  = t >> 1;
        const int jh = (t & 1) << 1;     // j = jh, jh+1
        const float4* ekr = (const float4*)(ek + ((size_t)(b * NN + i)) * DD);
        const int2 a2 = *(const int2*)(A + ((size_t)(b * NN + i)) * NN + j0 + jh);
        float acc0 = 0.f, acc1 = 0.f;
        #pragma unroll 4
        for (int d4 = 0; d4 < DD / 4; ++d4) {
            const float4 kv = ekr[d4];
            const float4 we = *(const float4*)&wes[d4 << 2];
            const float4 q0 = *(const float4*)&eqs[jh][d4 << 2];
            const float4 q1 = *(const float4*)&eqs[jh + 1][d4 << 2];
            acc0 += sigterm(kv.x, q0.x, we.x) + sigterm(kv.y, q0.y, we.y)
                  + sigterm(kv.z, q0.z, we.z) + sigterm(kv.w, q0.w, we.w);
            acc1 += sigterm(kv.x, q1.x, we.x) + sigterm(kv.y, q1.y, we.y)
                  + sigterm(kv.z, q1.z, we.z) + sigterm(kv.w, q1.w, we.w);
        }
        ssm[jh][i]     = (a2.x == 1) ? acc0 : C;
        ssm[jh + 1][i] = (a2.y == 1) ? acc1 : C;
    }
    __syncthreads();

    // ---- Phase C: softmax (waves 0-3, one j each) || stage v chunk 0 ----
    {
        const int wave = t >> 6;
        if (wave < 4) {
            const int c = t & 63;
            float vals[4];
            float mx = -1e30f;
            #pragma unroll
            for (int u = 0; u < 4; ++u) { vals[u] = ssm[wave][c + (u << 6)]; mx = fmaxf(mx, vals[u]); }
            #pragma unroll
            for (int o = 32; o > 0; o >>= 1) mx = fmaxf(mx, __shfl_xor(mx, o));
            float sum = 0.0f;
            #pragma unroll
            for (int u = 0; u < 4; ++u) { vals[u] = __expf(vals[u] - mx); sum += vals[u]; }
            #pragma unroll
            for (int o = 32; o > 0; o >>= 1) sum += __shfl_xor(sum, o);
            const float inv = __builtin_amdgcn_rcpf(sum);
            #pragma unroll
            for (int u = 0; u < 4; ++u) ssm[wave][c + (u << 6)] = vals[u] * inv;
        } else {
            const int t2 = t - 256;
            const float4* vg = (const float4*)(vv + (size_t)b * NN * DD);
            #pragma unroll
            for (int rep = 0; rep < 8; ++rep) {
                const int f = t2 + (rep << 8);          // 0..2047
                *(float4*)&vs[f >> 5][(f & 31) << 2] = vg[f];
            }
        }
    }
    __syncthreads();

    // ---- Phase D: thread = (j = t>>7, d = t&127); accumulate all 256 i ----
    const int jd = t >> 7, dp = t & 127;
    float oacc = 0.f;
    for (int ch = 0; ch < 4; ++ch) {
        if (ch > 0) {
            __syncthreads();
            const float4* vg = (const float4*)(vv + ((size_t)(b * NN) + (ch << 6)) * DD);
            #pragma unroll
            for (int rep = 0; rep < 4; ++rep) {
                const int f = t + (rep << 9);
                *(float4*)&vs[f >> 5][(f & 31) << 2] = vg[f];
            }
            __syncthreads();
        }
        #pragma unroll
        for (int ig = 0; ig < 16; ++ig) {
            // one broadcast b128 feeds 4 i-steps
            const float4 a4 = *(const float4*)&ssm[jd][(ch << 6) + (ig << 2)];
            oacc = fmaf(a4.x, vs[(ig << 2) + 0][dp], oacc);
            oacc = fmaf(a4.y, vs[(ig << 2) + 1][dp], oacc);
            oacc = fmaf(a4.z, vs[(ig << 2) + 2][dp], oacc);
            oacc = fmaf(a4.w, vs[(ig << 2) + 3][dp], oacc);
        }
    }
    out[((size_t)(b * NN) + j0 + jd) * DD + dp] = oacc;
}

extern "C" void kernel_launch(void* const* d_in, const int* in_sizes, int n_in,
                              void* d_out, int out_size, void* d_ws, size_t ws_size,
                              hipStream_t stream)
{
    const float* x  = (const float*)d_in[0];
    const int*   A  = (const int*)  d_in[1];
    const float* Wq = (const float*)d_in[2];
    const float* bq = (const float*)d_in[3];
    const float* Wk = (const float*)d_in[4];
    const float* Wv = (const float*)d_in[5];
    const float* We = (const float*)d_in[6];
    float* out = (float*)d_out;

    float* eq = (float*)d_ws;
    float* ek = eq + (size_t)BB * NN * DD;
    float* vv = ek + (size_t)BB * NN * DD;

    qkv_kernel<<<3 * BB * 8 * 2, 512, 0, stream>>>(x, Wq, bq, Wk, Wv, eq, ek, vv);
    attn_kernel<<<BB * (NN / 4), 512, 0, stream>>>(A, We, eq, ek, vv, out);
}

// Round 14
// 395.167 us; speedup vs baseline: 1.0489x; 1.0489x over previous
//
#include <hip/hip_runtime.h>

static constexpr int BB = 16;
static constexpr int NN = 256;
static constexpr int DD = 128;

__device__ __forceinline__ float sigterm(float kv, float q, float we) {
    // we * sigmoid(k+q) with ek=exp(-k), eq=exp(-q) precomputed: 1/(1+ek*eq)
    return we * __builtin_amdgcn_rcpf(fmaf(kv, q, 1.0f));
}

// Tiled GEMM: out[b,r,e] = sum_d x[b,r,d]*W[e,d] (+bias; exp(-.) for q,k).
// grid = 3m * 16b * 8 row-tiles * 2 e-halves = 768 blocks (3/CU), 512 thr.
__global__ __launch_bounds__(512) void qkv_kernel(
    const float* __restrict__ x,
    const float* __restrict__ Wq, const float* __restrict__ bq,
    const float* __restrict__ Wk, const float* __restrict__ Wv,
    float* __restrict__ eq, float* __restrict__ ek, float* __restrict__ vv)
{
    __shared__ float wlds[64 * DD];     // 64 e-rows x 128 d, swizzled (32KB)
    __shared__ float xlds[32][132];     // 32 rows x 128 d, padded (16.9KB)

    const int bid  = blockIdx.x;
    const int m    = bid % 3;
    const int rest = bid / 3;
    const int eh   = rest & 1;
    const int tile = rest >> 1;
    const int b    = tile >> 3;
    const int r0   = (tile & 7) << 5;
    const int t    = threadIdx.x;

    const float* W = (m == 0) ? Wq : (m == 1) ? Wk : Wv;
    float*      op = (m == 0) ? eq : (m == 1) ? ek : vv;

    char* wb = (char*)wlds;
    {
        const float4* wg = (const float4*)(W + (size_t)(eh * 64) * DD);
        #pragma unroll
        for (int rep = 0; rep < 4; ++rep) {
            const int idx = t + (rep << 9);
            const int e   = idx >> 5;
            const int c   = idx & 31;
            const int byte = e * 512 + c * 16;
            *(float4*)(wb + (byte ^ (((e >> 2) & 7) << 4))) = wg[idx];
        }
        const float4* xg = (const float4*)(x + ((size_t)(b * NN + r0)) * DD);
        #pragma unroll
        for (int rep = 0; rep < 2; ++rep) {
            const int idx = t + (rep << 9);
            *(float4*)&xlds[idx >> 5][(idx & 31) << 2] = xg[idx];
        }
    }
    __syncthreads();

    const int er = t & 15;
    const int rg = t >> 4;
    float4 acc = {0.f, 0.f, 0.f, 0.f};
    #pragma unroll 8
    for (int d4 = 0; d4 < DD / 4; ++d4) {
        const float4 xv = *(const float4*)&xlds[rg][d4 << 2];
        float4 w4[4];
        #pragma unroll
        for (int cc = 0; cc < 4; ++cc) {
            const int e = er * 4 + cc;
            const int byte = e * 512 + d4 * 16;
            w4[cc] = *(const float4*)(wb + (byte ^ (((e >> 2) & 7) << 4)));
        }
        acc.x = fmaf(xv.x, w4[0].x, fmaf(xv.y, w4[0].y, fmaf(xv.z, w4[0].z, fmaf(xv.w, w4[0].w, acc.x))));
        acc.y = fmaf(xv.x, w4[1].x, fmaf(xv.y, w4[1].y, fmaf(xv.z, w4[1].z, fmaf(xv.w, w4[1].w, acc.y))));
        acc.z = fmaf(xv.x, w4[2].x, fmaf(xv.y, w4[2].y, fmaf(xv.z, w4[2].z, fmaf(xv.w, w4[2].w, acc.z))));
        acc.w = fmaf(xv.x, w4[3].x, fmaf(xv.y, w4[3].y, fmaf(xv.z, w4[3].z, fmaf(xv.w, w4[3].w, acc.w))));
    }

    const int eg = eh * 64 + er * 4;
    float4 o = acc;
    if (m == 0) {
        const float4 b4 = *(const float4*)(bq + eg);
        o.x = __expf(-(o.x + b4.x)); o.y = __expf(-(o.y + b4.y));
        o.z = __expf(-(o.z + b4.z)); o.w = __expf(-(o.w + b4.w));
    } else if (m == 1) {
        o.x = __expf(-o.x); o.y = __expf(-o.y);
        o.z = __expf(-o.z); o.w = __expf(-o.w);
    }
    *(float4*)(op + ((size_t)(b * NN + r0 + rg)) * DD + eg) = o;
}

// grid = 16 b * 64 j-tiles = 1024 blocks, 512 threads, 4 j per block.
// LDS 40.6KB. __launch_bounds__(512, 4): proven no-spill cap (R7 ",8" -> 66MB
// spill writes; R12 ",6" -> 667MB spill writes; ",4" clean in R8/R10).
// No Phase-D reduce: thread = (j, d) accumulates over all 256 i.
__global__ __launch_bounds__(512, 4) void attn_kernel(
    const int* __restrict__ A, const float* __restrict__ We,
    const float* __restrict__ eq, const float* __restrict__ ek,
    const float* __restrict__ vv, float* __restrict__ out)
{
    __shared__ float vs[64][132];    // v chunk (33792 B)
    __shared__ float eqs[4][132];    // 2112 B
    __shared__ float wes[DD];        // 512 B
    __shared__ float ssm[4][260];    // 4160 B
    __shared__ float smC;

    // bijective XCD swizzle: 1024 wgs / 8 XCDs = 128 contiguous per XCD
    const int bid = (int)((blockIdx.x & 7) * 128 + (blockIdx.x >> 3));
    const int b  = bid >> 6;
    const int j0 = (bid & 63) << 2;
    const int t  = threadIdx.x;

    // ---- Phase A: stage 4 q-rows + We; wave 7 computes C = 0.5*sum(We) ----
    if (t < 128) {
        const int row = t >> 5, col = (t & 31) << 2;
        *(float4*)&eqs[row][col] =
            *(const float4*)(eq + ((size_t)(b * NN + j0 + row)) * DD + col);
    } else if (t < 160) {
        const int l = t - 128;
        *(float4*)&wes[l << 2] = ((const float4*)We)[l];
    } else if (t >= 448) {
        const int lane = t - 448;
        float w = We[lane] + We[lane + 64];
        #pragma unroll
        for (int o = 32; o > 0; o >>= 1) w += __shfl_xor(w, o);
        if (lane == 0) smC = 0.5f * w;
    }
    __syncthreads();

    // ---- Phase B: thread = (i, 2 j's). 8 sigterms/iter; trans-pipe bound. ----
    {
        const float C = smC;
        const int i  = t >> 1;
        const int jh = (t & 1) << 1;     // j = jh, jh+1
        const float4* ekr = (const float4*)(ek + ((size_t)(b * NN + i)) * DD);
        const int2 a2 = *(const int2*)(A + ((size_t)(b * NN + i)) * NN + j0 + jh);
        float acc0 = 0.f, acc1 = 0.f;
        #pragma unroll 4
        for (int d4 = 0; d4 < DD / 4; ++d4) {
            const float4 kv = ekr[d4];
            const float4 we = *(const float4*)&wes[d4 << 2];
            const float4 q0 = *(const float4*)&eqs[jh][d4 << 2];
            const float4 q1 = *(const float4*)&eqs[jh + 1][d4 << 2];
            acc0 += sigterm(kv.x, q0.x, we.x) + sigterm(kv.y, q0.y, we.y)
                  + sigterm(kv.z, q0.z, we.z) + sigterm(kv.w, q0.w, we.w);
            acc1 += sigterm(kv.x, q1.x, we.x) + sigterm(kv.y, q1.y, we.y)
                  + sigterm(kv.z, q1.z, we.z) + sigterm(kv.w, q1.w, we.w);
        }
        ssm[jh][i]     = (a2.x == 1) ? acc0 : C;
        ssm[jh + 1][i] = (a2.y == 1) ? acc1 : C;
    }
    __syncthreads();

    // ---- Phase C: softmax (waves 0-3, one j each) || stage v chunk 0 ----
    {
        const int wave = t >> 6;
        if (wave < 4) {
            const int c = t & 63;
            float vals[4];
            float mx = -1e30f;
            #pragma unroll
            for (int u = 0; u < 4; ++u) { vals[u] = ssm[wave][c + (u << 6)]; mx = fmaxf(mx, vals[u]); }
            #pragma unroll
            for (int o = 32; o > 0; o >>= 1) mx = fmaxf(mx, __shfl_xor(mx, o));
            float sum = 0.0f;
            #pragma unroll
            for (int u = 0; u < 4; ++u) { vals[u] = __expf(vals[u] - mx); sum += vals[u]; }
            #pragma unroll
            for (int o = 32; o > 0; o >>= 1) sum += __shfl_xor(sum, o);
            const float inv = __builtin_amdgcn_rcpf(sum);
            #pragma unroll
            for (int u = 0; u < 4; ++u) ssm[wave][c + (u << 6)] = vals[u] * inv;
        } else {
            const int t2 = t - 256;
            const float4* vg = (const float4*)(vv + (size_t)b * NN * DD);
            #pragma unroll
            for (int rep = 0; rep < 8; ++rep) {
                const int f = t2 + (rep << 8);          // 0..2047
                *(float4*)&vs[f >> 5][(f & 31) << 2] = vg[f];
            }
        }
    }
    __syncthreads();

    // ---- Phase D: thread = (j = t>>7, d = t&127); accumulate all 256 i ----
    const int jd = t >> 7, dp = t & 127;
    float oacc = 0.f;
    for (int ch = 0; ch < 4; ++ch) {
        if (ch > 0) {
            __syncthreads();
            const float4* vg = (const float4*)(vv + ((size_t)(b * NN) + (ch << 6)) * DD);
            #pragma unroll
            for (int rep = 0; rep < 4; ++rep) {
                const int f = t + (rep << 9);
                *(float4*)&vs[f >> 5][(f & 31) << 2] = vg[f];
            }
            __syncthreads();
        }
        #pragma unroll
        for (int ig = 0; ig < 16; ++ig) {
            // one broadcast b128 feeds 4 i-steps
            const float4 a4 = *(const float4*)&ssm[jd][(ch << 6) + (ig << 2)];
            oacc = fmaf(a4.x, vs[(ig << 2) + 0][dp], oacc);
            oacc = fmaf(a4.y, vs[(ig << 2) + 1][dp], oacc);
            oacc = fmaf(a4.z, vs[(ig << 2) + 2][dp], oacc);
            oacc = fmaf(a4.w, vs[(ig << 2) + 3][dp], oacc);
        }
    }
    out[((size_t)(b * NN) + j0 + jd) * DD + dp] = oacc;
}

extern "C" void kernel_launch(void* const* d_in, const int* in_sizes, int n_in,
                              void* d_out, int out_size, void* d_ws, size_t ws_size,
                              hipStream_t stream)
{
    const float* x  = (const float*)d_in[0];
    const int*   A  = (const int*)  d_in[1];
    const float* Wq = (const float*)d_in[2];
    const float* bq = (const float*)d_in[3];
    const float* Wk = (const float*)d_in[4];
    const float* Wv = (const float*)d_in[5];
    const float* We = (const float*)d_in[6];
    float* out = (float*)d_out;

    float* eq = (float*)d_ws;
    float* ek = eq + (size_t)BB * NN * DD;
    float* vv = ek + (size_t)BB * NN * DD;

    qkv_kernel<<<3 * BB * 8 * 2, 512, 0, stream>>>(x, Wq, bq, Wk, Wv, eq, ek, vv);
    attn_kernel<<<BB * (NN / 4), 512, 0, stream>>>(A, We, eq, ek, vv, out);
}

// Round 16
// 111.963 us; speedup vs baseline: 3.7021x; 3.5294x over previous
//
#include <hip/hip_runtime.h>

static constexpr int BB = 16;
static constexpr int NN = 256;
static constexpr int DD = 128;

__device__ __forceinline__ float sigterm(float kv, float q, float we) {
    // we * sigmoid(k+q) with ek=exp(-k), eq=exp(-q) precomputed: 1/(1+ek*eq)
    return we * __builtin_amdgcn_rcpf(fmaf(kv, q, 1.0f));
}

// Tiled GEMM: out[b,r,e] = sum_d x[b,r,d]*W[e,d] (+bias; exp(-.) for q,k).
// grid = 3m * 16b * 8 row-tiles * 2 e-halves = 768 blocks (3/CU), 512 thr.
// Measured clean in R10 (<44us, no spills).
__global__ __launch_bounds__(512) void qkv_kernel(
    const float* __restrict__ x,
    const float* __restrict__ Wq, const float* __restrict__ bq,
    const float* __restrict__ Wk, const float* __restrict__ Wv,
    float* __restrict__ eq, float* __restrict__ ek, float* __restrict__ vv)
{
    __shared__ float wlds[64 * DD];     // 64 e-rows x 128 d, swizzled (32KB)
    __shared__ float xlds[32][132];     // 32 rows x 128 d, padded (16.9KB)

    const int bid  = blockIdx.x;
    const int m    = bid % 3;
    const int rest = bid / 3;
    const int eh   = rest & 1;
    const int tile = rest >> 1;
    const int b    = tile >> 3;
    const int r0   = (tile & 7) << 5;
    const int t    = threadIdx.x;

    const float* W = (m == 0) ? Wq : (m == 1) ? Wk : Wv;
    float*      op = (m == 0) ? eq : (m == 1) ? ek : vv;

    char* wb = (char*)wlds;
    {
        const float4* wg = (const float4*)(W + (size_t)(eh * 64) * DD);
        #pragma unroll
        for (int rep = 0; rep < 4; ++rep) {
            const int idx = t + (rep << 9);
            const int e   = idx >> 5;
            const int c   = idx & 31;
            const int byte = e * 512 + c * 16;
            *(float4*)(wb + (byte ^ (((e >> 2) & 7) << 4))) = wg[idx];
        }
        const float4* xg = (const float4*)(x + ((size_t)(b * NN + r0)) * DD);
        #pragma unroll
        for (int rep = 0; rep < 2; ++rep) {
            const int idx = t + (rep << 9);
            *(float4*)&xlds[idx >> 5][(idx & 31) << 2] = xg[idx];
        }
    }
    __syncthreads();

    const int er = t & 15;
    const int rg = t >> 4;
    float4 acc = {0.f, 0.f, 0.f, 0.f};
    #pragma unroll 8
    for (int d4 = 0; d4 < DD / 4; ++d4) {
        const float4 xv = *(const float4*)&xlds[rg][d4 << 2];
        float4 w4[4];
        #pragma unroll
        for (int cc = 0; cc < 4; ++cc) {
            const int e = er * 4 + cc;
            const int byte = e * 512 + d4 * 16;
            w4[cc] = *(const float4*)(wb + (byte ^ (((e >> 2) & 7) << 4)));
        }
        acc.x = fmaf(xv.x, w4[0].x, fmaf(xv.y, w4[0].y, fmaf(xv.z, w4[0].z, fmaf(xv.w, w4[0].w, acc.x))));
        acc.y = fmaf(xv.x, w4[1].x, fmaf(xv.y, w4[1].y, fmaf(xv.z, w4[1].z, fmaf(xv.w, w4[1].w, acc.y))));
        acc.z = fmaf(xv.x, w4[2].x, fmaf(xv.y, w4[2].y, fmaf(xv.z, w4[2].z, fmaf(xv.w, w4[2].w, acc.z))));
        acc.w = fmaf(xv.x, w4[3].x, fmaf(xv.y, w4[3].y, fmaf(xv.z, w4[3].z, fmaf(xv.w, w4[3].w, acc.w))));
    }

    const int eg = eh * 64 + er * 4;
    float4 o = acc;
    if (m == 0) {
        const float4 b4 = *(const float4*)(bq + eg);
        o.x = __expf(-(o.x + b4.x)); o.y = __expf(-(o.y + b4.y));
        o.z = __expf(-(o.z + b4.z)); o.w = __expf(-(o.w + b4.w));
    } else if (m == 1) {
        o.x = __expf(-o.x); o.y = __expf(-o.y);
        o.z = __expf(-o.z); o.w = __expf(-o.w);
    }
    *(float4*)(op + ((size_t)(b * NN + r0 + rg)) * DD + eg) = o;
}

// grid = 16 b * 64 j-tiles = 1024 blocks, 512 threads, 4 j per block.
// R7-submission attn body, measured CLEAN at (512,4) in R8 bench (<42us,
// no spills, total 106.2). Do NOT change structure or bounds: the 4j
// no-reduce variant (R12/R14) spills catastrophically at every bound.
__global__ __launch_bounds__(512, 4) void attn_kernel(
    const int* __restrict__ A, const float* __restrict__ We,
    const float* __restrict__ eq, const float* __restrict__ ek,
    const float* __restrict__ vv, float* __restrict__ out)
{
    __shared__ float vs[64][132];    // v chunk; reused as reduction buffer (33792 B)
    __shared__ float eqs[4][132];
    __shared__ float wes[DD];
    __shared__ float ssm[4][264];
    __shared__ float smC;

    // bijective XCD swizzle: 1024 wgs / 8 XCDs = 128 contiguous per XCD
    const int bid = (int)((blockIdx.x & 7) * 128 + (blockIdx.x >> 3));
    const int b  = bid >> 6;
    const int j0 = (bid & 63) << 2;
    const int t  = threadIdx.x;

    // ---- Phase A: stage 4 q-rows + We; wave 7 computes C = 0.5*sum(We) ----
    if (t < 128) {
        const int row = t >> 5, col = (t & 31) << 2;
        *(float4*)&eqs[row][col] =
            *(const float4*)(eq + ((size_t)(b * NN + j0 + row)) * DD + col);
    } else if (t < 160) {
        const int l = t - 128;
        *(float4*)&wes[l << 2] = ((const float4*)We)[l];
    } else if (t >= 448) {
        const int lane = t - 448;
        float w = We[lane] + We[lane + 64];
        #pragma unroll
        for (int o = 32; o > 0; o >>= 1) w += __shfl_xor(w, o);
        if (lane == 0) smC = 0.5f * w;
    }
    __syncthreads();

    // ---- Phase B: all 256 i in one pass, 2 adjacent j per thread ----
    {
        const float C = smC;
        const int i  = t >> 1;
        const int jA = (t & 1) << 1;     // j = jA, jA+1
        const float4* ekr = (const float4*)(ek + ((size_t)(b * NN + i)) * DD);
        const int2 a2 = *(const int2*)(A + ((size_t)(b * NN + i)) * NN + j0 + jA);
        float acc0 = 0.f, acc1 = 0.f;
        #pragma unroll 4
        for (int d4 = 0; d4 < DD / 4; ++d4) {
            const float4 kv = ekr[d4];
            const float4 we = *(const float4*)&wes[d4 << 2];
            const float4 q0 = *(const float4*)&eqs[jA][d4 << 2];
            const float4 q1 = *(const float4*)&eqs[jA + 1][d4 << 2];
            acc0 += sigterm(kv.x, q0.x, we.x) + sigterm(kv.y, q0.y, we.y)
                  + sigterm(kv.z, q0.z, we.z) + sigterm(kv.w, q0.w, we.w);
            acc1 += sigterm(kv.x, q1.x, we.x) + sigterm(kv.y, q1.y, we.y)
                  + sigterm(kv.z, q1.z, we.z) + sigterm(kv.w, q1.w, we.w);
        }
        ssm[jA][i]     = (a2.x == 1) ? acc0 : C;
        ssm[jA + 1][i] = (a2.y == 1) ? acc1 : C;
    }
    __syncthreads();

    // ---- Phase C: softmax (waves 0-3) || stage v chunk 0 (waves 4-7) ----
    {
        const int wave = t >> 6;
        if (wave < 4) {
            const int c = t & 63;
            float vals[4];
            float mx = -1e30f;
            #pragma unroll
            for (int u = 0; u < 4; ++u) { vals[u] = ssm[wave][c + (u << 6)]; mx = fmaxf(mx, vals[u]); }
            #pragma unroll
            for (int o = 32; o > 0; o >>= 1) mx = fmaxf(mx, __shfl_xor(mx, o));
            float sum = 0.0f;
            #pragma unroll
            for (int u = 0; u < 4; ++u) { vals[u] = __expf(vals[u] - mx); sum += vals[u]; }
            #pragma unroll
            for (int o = 32; o > 0; o >>= 1) sum += __shfl_xor(sum, o);
            const float inv = __builtin_amdgcn_rcpf(sum);
            #pragma unroll
            for (int u = 0; u < 4; ++u) ssm[wave][c + (u << 6)] = vals[u] * inv;
        } else {
            const int t2 = t - 256;
            const float4* vg = (const float4*)(vv + (size_t)b * NN * DD);
            #pragma unroll
            for (int rep = 0; rep < 8; ++rep) {
                const int f = t2 + (rep << 8);          // 0..2047 over 8 reps
                *(float4*)&vs[f >> 5][(f & 31) << 2] = vg[f];
            }
        }
    }
    __syncthreads();

    // ---- Phase D: 4 chunks of 64 i; reg-reuse v4 across 4 j ----
    const int c4 = t & 31;       // d = c4*4 .. c4*4+3
    const int ig = t >> 5;       // 16 i-groups of 4
    float4 pa0 = {0,0,0,0}, pa1 = {0,0,0,0}, pa2 = {0,0,0,0}, pa3 = {0,0,0,0};
    for (int ch = 0; ch < 4; ++ch) {
        #pragma unroll
        for (int ii = 0; ii < 4; ++ii) {
            const int il = (ig << 2) + ii;
            const int i  = (ch << 6) + il;
            const float4 v4 = *(const float4*)&vs[il][c4 << 2];
            const float a0 = ssm[0][i], a1 = ssm[1][i], a2 = ssm[2][i], a3 = ssm[3][i];
            pa0.x = fmaf(a0, v4.x, pa0.x); pa0.y = fmaf(a0, v4.y, pa0.y);
            pa0.z = fmaf(a0, v4.z, pa0.z); pa0.w = fmaf(a0, v4.w, pa0.w);
            pa1.x = fmaf(a1, v4.x, pa1.x); pa1.y = fmaf(a1, v4.y, pa1.y);
            pa1.z = fmaf(a1, v4.z, pa1.z); pa1.w = fmaf(a1, v4.w, pa1.w);
            pa2.x = fmaf(a2, v4.x, pa2.x); pa2.y = fmaf(a2, v4.y, pa2.y);
            pa2.z = fmaf(a2, v4.z, pa2.z); pa2.w = fmaf(a2, v4.w, pa2.w);
            pa3.x = fmaf(a3, v4.x, pa3.x); pa3.y = fmaf(a3, v4.y, pa3.y);
            pa3.z = fmaf(a3, v4.z, pa3.z); pa3.w = fmaf(a3, v4.w, pa3.w);
        }
        if (ch < 3) {
            __syncthreads();
            const float4* vg = (const float4*)(vv + ((size_t)(b * NN) + ((ch + 1) << 6)) * DD);
            #pragma unroll
            for (int rep = 0; rep < 4; ++rep) {
                const int f = t + (rep << 9);           // 0..2047 over 4 reps
                *(float4*)&vs[f >> 5][(f & 31) << 2] = vg[f];
            }
            __syncthreads();
        }
    }
    __syncthreads();                                    // vs reads done -> reuse as red

    // ---- reduce 16 partials per (j,d), then store ----
    float* red = &vs[0][0];                             // [16][512] floats = 32KB
    *(float4*)&red[ig * 512 +   0 + (c4 << 2)] = pa0;
    *(float4*)&red[ig * 512 + 128 + (c4 << 2)] = pa1;
    *(float4*)&red[ig * 512 + 256 + (c4 << 2)] = pa2;
    *(float4*)&red[ig * 512 + 384 + (c4 << 2)] = pa3;
    __syncthreads();
    float s = 0.f;
    #pragma unroll
    for (int g = 0; g < 16; ++g) s += red[g * 512 + t];
    out[((size_t)(b * NN) + j0 + (t >> 7)) * DD + (t & 127)] = s;
}

extern "C" void kernel_launch(void* const* d_in, const int* in_sizes, int n_in,
                              void* d_out, int out_size, void* d_ws, size_t ws_size,
                              hipStream_t stream)
{
    const float* x  = (const float*)d_in[0];
    const int*   A  = (const int*)  d_in[1];
    const float* Wq = (const float*)d_in[2];
    const float* bq = (const float*)d_in[3];
    const float* Wk = (const float*)d_in[4];
    const float* Wv = (const float*)d_in[5];
    const float* We = (const float*)d_in[6];
    float* out = (float*)d_out;

    float* eq = (float*)d_ws;
    float* ek = eq + (size_t)BB * NN * DD;
    float* vv = ek + (size_t)BB * NN * DD;

    qkv_kernel<<<3 * BB * 8 * 2, 512, 0, stream>>>(x, Wq, bq, Wk, Wv, eq, ek, vv);
    attn_kernel<<<BB * (NN / 4), 512, 0, stream>>>(A, We, eq, ek, vv, out);
}